// Round 12
// baseline (350.302 us; speedup 1.0000x reference)
//
#include <hip/hip_runtime.h>
#include <math.h>

#define NN 100000
#define EE 1600000
#define GG 512
#define INF_ 128
#define HID 64
#define EPS 1e-5f

#define NBUK 391          // ceil(NN/256), bucket = dst >> 8
#define P1T 196           // CSR tiles: 2048 int4 = 8192 edges each
#define SETUP_B 25        // covers setup span (6240 < 25*256)
#define POOL_WORDS (GG * 64 * 2 + GG)
#define ZERO_B ((POOL_WORDS + 255) / 256)
#define P2CAP 5120        // LDS stage cap per bucket (mean 4096, std 64)

typedef unsigned int uint32;
typedef __attribute__((ext_vector_type(8))) short bf16x8;
typedef __attribute__((ext_vector_type(4))) float f32x4;

// bf16 helpers: RNE pack, shift decode
static __device__ inline uint32 f2bf(float f) {
    uint32 u = __float_as_uint(f);
    return (u + 0x7FFFu + ((u >> 16) & 1u)) >> 16;
}
static __device__ inline float bf_lo(uint32 u) { return __uint_as_float(u << 16); }
static __device__ inline float bf_hi(uint32 u) { return __uint_as_float(u & 0xFFFF0000u); }

// R10: edge weight folded into features (hw' = hw*dinv[row]); tails -> row NN.
// R11: 32-lane/2-segment gather layout; activations packed bf16.
// R12: p1b/p2 scatters staged in LDS -> contiguous global writes (the 4B
// scattered writes were the hypothesized hidden ~60us); p1b reuses hblk
// counts instead of re-histogramming.

// blocks [0,P1T): per-block dst histogram. then setup. rest: zero pool.
__global__ __launch_bounds__(256) void k_hist1(const int* __restrict__ ei,
        int* __restrict__ hblk,
        const float* b1, const float* g1, const float* be1,
        const float* rm1, const float* rv1,
        const float* b2, const float* g2, const float* be2,
        const float* rm2, const float* rv2, float* sc,
        const float* W1, uint32* Wt1b, const float* W2, uint32* Wt2b,
        uint32* hwb, float* poolz) {
    int b = blockIdx.x, t = threadIdx.x;
    if (b < P1T) {
        __shared__ int h[NBUK];
        for (int i = t; i < NBUK; i += 256) h[i] = 0;
        __syncthreads();
        const int4* dst4 = (const int4*)(ei + EE);
        int base4 = b * 2048;
        for (int j = 0; j < 8; ++j) {
            int i4 = base4 + j * 256 + t;
            if (i4 < EE / 4) {
                int4 d = dst4[i4];
                atomicAdd(&h[d.x >> 8], 1);
                atomicAdd(&h[d.y >> 8], 1);
                atomicAdd(&h[d.z >> 8], 1);
                atomicAdd(&h[d.w >> 8], 1);
            }
        }
        __syncthreads();
        for (int i = t; i < NBUK; i += 256) hblk[i * P1T + b] = h[i];
    } else if (b < P1T + SETUP_B) {
        int i = (b - P1T) * 256 + t;
        if (i < 4096) {                       // Wt1b: K=128
            int n = i >> 6, kp = (i & 63) * 2;
            Wt1b[i] = f2bf(W1[(size_t)kp * 64 + n]) |
                      (f2bf(W1[(size_t)(kp + 1) * 64 + n]) << 16);
        } else if (i < 6144) {                // Wt2b: K=64
            int j = i - 4096;
            int n = j >> 5, kp = (j & 31) * 2;
            Wt2b[j] = f2bf(W2[(size_t)kp * 64 + n]) |
                      (f2bf(W2[(size_t)(kp + 1) * 64 + n]) << 16);
        } else if (i < 6208) {                // BN fold
            int l = i - 6144;
            float s1 = g1[l] * rsqrtf(rv1[l] + EPS);
            sc[l]       = s1;
            sc[64 + l]  = (b1[l] - rm1[l]) * s1 + be1[l];
            float s2 = g2[l] * rsqrtf(rv2[l] + EPS);
            sc[128 + l] = s2;
            sc[192 + l] = (b2[l] - rm2[l]) * s2 + be2[l];
        } else if (i < 6240) {                // zero row NN of hwb
            hwb[(size_t)NN * 32 + (i - 6208)] = 0u;
        }
    } else {
        int i = (b - P1T - SETUP_B) * 256 + t;
        if (i < POOL_WORDS) poolz[i] = 0.f;
    }
}

// one block, 512 threads: bucket totals + scan -> bbase; per-block run bases.
__global__ void k_scan2(const int* __restrict__ hblk, int* __restrict__ bbase,
                        int* __restrict__ rbase, int* __restrict__ offs) {
    __shared__ int wsum[8];
    int t = threadIdx.x;  // 512
    int lane = t & 63, w = t >> 6;
    int c = 0;
    if (t < NBUK)
        for (int b = 0; b < P1T; ++b) c += hblk[t * P1T + b];
    int v = c;
    for (int d = 1; d < 64; d <<= 1) { int n = __shfl_up(v, d); if (lane >= d) v += n; }
    if (lane == 63) wsum[w] = v;
    __syncthreads();
    int pre = 0;
    for (int q = 0; q < w; ++q) pre += wsum[q];
    int excl = pre + v - c;
    if (t <= NBUK) bbase[t] = excl;
    if (t == 0) offs[NN] = EE;
    if (t < NBUK) {
        int run = excl;
        for (int b = 0; b < P1T; ++b) {
            rbase[t * P1T + b] = run;
            run += hblk[t * P1T + b];
        }
    }
}

// scatter packed (src<<8)|(dst&255) via LDS stage -> contiguous run writes.
__global__ __launch_bounds__(256) void k_p1b(const int* __restrict__ ei,
                                             const int* __restrict__ hblk,
                                             const int* __restrict__ rbase,
                                             uint32* __restrict__ pairs) {
    __shared__ uint32 stage[8192];    // 32 KB
    __shared__ int hloc[NBUK];        // counts (preserved for copyout)
    __shared__ int lbase[NBUK];       // local exclusive base
    __shared__ int cur[NBUK];         // scatter cursor
    __shared__ int wsum[4];
    int b = blockIdx.x, t = threadIdx.x;
    int lane = t & 63, w = t >> 6;
    for (int i = t; i < NBUK; i += 256) hloc[i] = hblk[i * P1T + b];
    __syncthreads();
    // 2-round exclusive scan of hloc (391 entries, 256 threads)
    int carry = 0;
    for (int r = 0; r < 2; ++r) {
        int idx = r * 256 + t;
        int c = (idx < NBUK) ? hloc[idx] : 0;
        int v = c;
        for (int d = 1; d < 64; d <<= 1) { int n = __shfl_up(v, d); if (lane >= d) v += n; }
        if (lane == 63) wsum[w] = v;
        __syncthreads();
        int pre = 0;
        for (int q = 0; q < w; ++q) pre += wsum[q];
        int excl = pre + v - c + carry;
        if (idx < NBUK) { lbase[idx] = excl; cur[idx] = excl; }
        carry += wsum[0] + wsum[1] + wsum[2] + wsum[3];
        __syncthreads();
    }
    const int4* src4 = (const int4*)ei;
    const int4* dst4 = (const int4*)(ei + EE);
    int base4 = b * 2048;
    for (int j = 0; j < 8; ++j) {
        int i4 = base4 + j * 256 + t;
        if (i4 < EE / 4) {
            int4 d = dst4[i4];
            int4 s = src4[i4];
            int p0 = atomicAdd(&cur[d.x >> 8], 1);
            stage[p0] = ((uint32)s.x << 8) | (uint32)(d.x & 255);
            int p1 = atomicAdd(&cur[d.y >> 8], 1);
            stage[p1] = ((uint32)s.y << 8) | (uint32)(d.y & 255);
            int p2 = atomicAdd(&cur[d.z >> 8], 1);
            stage[p2] = ((uint32)s.z << 8) | (uint32)(d.z & 255);
            int p3 = atomicAdd(&cur[d.w >> 8], 1);
            stage[p3] = ((uint32)s.w << 8) | (uint32)(d.w & 255);
        }
    }
    __syncthreads();
    // copyout: wave wv handles buckets wv, wv+4, ... contiguous runs
    for (int k = w; k < NBUK; k += 4) {
        int len = hloc[k];
        if (!len) continue;
        int gdst = rbase[k * P1T + b];
        int lsrc = lbase[k];
        for (int i = lane; i < len; i += 64)
            pairs[gdst + i] = stage[lsrc + i];
    }
}

// per-bucket (256 nodes) CSR finalize fully in LDS; coalesced col writes.
__global__ __launch_bounds__(256) void k_p2(const uint32* __restrict__ pairs,
                                            const int* __restrict__ bbase,
                                            int* __restrict__ offs, float* __restrict__ dinv,
                                            int* __restrict__ col) {
    __shared__ uint32 pL[P2CAP];
    __shared__ int colL[P2CAP];
    __shared__ int cnt[256];
    __shared__ int wsum[4];
    int b = blockIdx.x, t = threadIdx.x;
    int nbase = b << 8;
    int ebase = bbase[b], eend = bbase[b + 1];
    int m = eend - ebase;
    int mm = m < P2CAP ? m : P2CAP;
    for (int i = t; i < mm; i += 256) pL[i] = pairs[ebase + i];
    cnt[t] = 0;
    __syncthreads();
    for (int i = t; i < mm; i += 256) atomicAdd(&cnt[pL[i] & 255u], 1);
    for (int i = P2CAP + t; i < m; i += 256) atomicAdd(&cnt[pairs[ebase + i] & 255u], 1);
    __syncthreads();
    int c = cnt[t];
    int lane = t & 63, w = t >> 6;
    int v = c;
    for (int d = 1; d < 64; d <<= 1) { int n = __shfl_up(v, d); if (lane >= d) v += n; }
    if (lane == 63) wsum[w] = v;
    __syncthreads();
    int pre = 0;
    for (int q = 0; q < w; ++q) pre += wsum[q];
    int excl = pre + v - c;
    int node = nbase + t;
    if (node < NN) {
        offs[node] = ebase + excl;
        dinv[node] = rsqrtf(1.f + (float)c);
    }
    __syncthreads();
    cnt[t] = excl;
    __syncthreads();
    for (int i = t; i < mm; i += 256) {
        uint32 u = pL[i];
        int loc = atomicAdd(&cnt[u & 255u], 1);
        if (loc < P2CAP) colL[loc] = (int)(u >> 8);
        else col[ebase + loc] = (int)(u >> 8);
    }
    for (int i = P2CAP + t; i < m; i += 256) {
        uint32 u = pairs[ebase + i];
        int loc = atomicAdd(&cnt[u & 255u], 1);
        if (loc < P2CAP) colL[loc] = (int)(u >> 8);
        else col[ebase + loc] = (int)(u >> 8);
    }
    __syncthreads();
    for (int i = t; i < mm; i += 256) col[ebase + i] = colL[i];
}

// ------ MFMA GEMM: X @ [K,64]bf16, rows pre-scaled by dinv -> bf16 packed --
// XBF16=0: X f32 [nrows][K]. XBF16=1: X bf16-packed uint [nrows][K/2].
// Rows padded +8 bf16: frag loads 2-way bank alias (free, m136).
template <int K, int XBF16>
__global__ __launch_bounds__(256) void k_gemm_mfma(const void* __restrict__ Xv,
                                                   const uint32* __restrict__ Wtb,
                                                   const float* __restrict__ dinv,
                                                   uint32* __restrict__ outb, int nrows) {
    constexpr int KP = K + 8;
    __shared__ alignas(16) unsigned short Al[64 * KP];
    __shared__ alignas(16) unsigned short Bl[64 * KP];
    int tid = threadIdx.x;
    for (int i = tid; i < 64 * (K / 2); i += 256) {
        int n = i / (K / 2), kp = i % (K / 2);
        *(uint32*)&Bl[n * KP + kp * 2] = Wtb[i];
    }
    int r0 = blockIdx.x * 64;
    if (XBF16 == 0) {
        const float* Xb = (const float*)Xv + (size_t)r0 * K;
        int limit = (nrows - r0) * K;
        for (int f = tid * 4; f < 64 * K; f += 1024) {
            float4 v = {0.f, 0.f, 0.f, 0.f};
            if (f + 3 < limit) v = *(const float4*)&Xb[f];
            int row = f / K, kpos = f % K;
            ushort4 pk;
            pk.x = (unsigned short)f2bf(v.x);
            pk.y = (unsigned short)f2bf(v.y);
            pk.z = (unsigned short)f2bf(v.z);
            pk.w = (unsigned short)f2bf(v.w);
            *(ushort4*)&Al[row * KP + kpos] = pk;
        }
    } else {
        const uint32* Xb = (const uint32*)Xv;
        for (int i = tid; i < 64 * (K / 2); i += 256) {
            int row = i / (K / 2), c = i % (K / 2);
            uint32 v = 0;
            if (r0 + row < nrows) v = Xb[(size_t)(r0 + row) * (K / 2) + c];
            *(uint32*)&Al[row * KP + 2 * c] = v;
        }
    }
    __syncthreads();
    int lane = tid & 63, wv = tid >> 6;
    int m = lane & 15, quad = lane >> 4;
    f32x4 acc0 = {0.f, 0.f, 0.f, 0.f}, acc1 = acc0, acc2 = acc0, acc3 = acc0;
    int arow = wv * 16 + m;
#pragma unroll
    for (int k0 = 0; k0 < K; k0 += 32) {
        int koff = k0 + quad * 8;
        bf16x8 a = *(const bf16x8*)&Al[arow * KP + koff];
        bf16x8 b0 = *(const bf16x8*)&Bl[(0 * 16 + m) * KP + koff];
        bf16x8 b1 = *(const bf16x8*)&Bl[(1 * 16 + m) * KP + koff];
        bf16x8 b2 = *(const bf16x8*)&Bl[(2 * 16 + m) * KP + koff];
        bf16x8 b3 = *(const bf16x8*)&Bl[(3 * 16 + m) * KP + koff];
        acc0 = __builtin_amdgcn_mfma_f32_16x16x32_bf16(a, b0, acc0, 0, 0, 0);
        acc1 = __builtin_amdgcn_mfma_f32_16x16x32_bf16(a, b1, acc1, 0, 0, 0);
        acc2 = __builtin_amdgcn_mfma_f32_16x16x32_bf16(a, b2, acc2, 0, 0, 0);
        acc3 = __builtin_amdgcn_mfma_f32_16x16x32_bf16(a, b3, acc3, 0, 0, 0);
    }
    // C/D layout: col = nt*16 + m, row = quad*4 + reg.
    float dsc[4];
#pragma unroll
    for (int reg = 0; reg < 4; ++reg) {
        int row = r0 + wv * 16 + quad * 4 + reg;
        dsc[reg] = (row < nrows) ? dinv[row] : 0.f;
    }
    const float* accs[4] = {(const float*)&acc0, (const float*)&acc1,
                            (const float*)&acc2, (const float*)&acc3};
#pragma unroll
    for (int nt = 0; nt < 4; ++nt) {
#pragma unroll
        for (int reg = 0; reg < 4; ++reg) {
            float val = accs[nt][reg] * dsc[reg];
            float nxt = __shfl_down(val, 1);
            int row = r0 + wv * 16 + quad * 4 + reg;
            if (((m & 1) == 0) && row < nrows)
                outb[(size_t)row * 32 + nt * 8 + (m >> 1)] =
                    f2bf(val) | (f2bf(nxt) << 16);
        }
    }
}

// ---- fused GCN aggregate + selfloop + BN + ReLU (+resid), weight-folded ---
// One wave per node; 32 lanes x uint cover the 128B bf16 row, 2 halves =
// 2 rows per load instruction; 16 edges/iter = 8 shfl + 8 loads + 16 adds.
// Tail slots read zeroed row NN. Output packed bf16 [NN][32].
__global__ void k_gcn_gather(const uint32* __restrict__ hwb, const int* __restrict__ col,
                             const int* __restrict__ offs,
                             const float* __restrict__ dinv, const float* __restrict__ scale,
                             const float* __restrict__ shift, const uint32* __restrict__ resid,
                             uint32* __restrict__ outb) {
    int node = blockIdx.x * 4 + (threadIdx.x >> 6);
    if (node >= NN) return;
    int lane = threadIdx.x & 63;
    int half = lane >> 5;
    int fl = lane & 31;                 // feature pair: {2fl, 2fl+1}
    int e0 = offs[node], e1 = offs[node + 1];
    float di = dinv[node];
    float ax0 = 0.f, ay0 = 0.f, ax1 = 0.f, ay1 = 0.f;
    for (int base = e0; base < e1; base += 64) {
        int m = e1 - base; if (m > 64) m = 64;
        int srcv = NN;                  // zero row for tail slots
        if (lane < m) srcv = col[base + lane];
        for (int j = 0; j < m; j += 16) {
            int s0 = __shfl(srcv, j + half);
            int s1 = __shfl(srcv, j + 2 + half);
            int s2 = __shfl(srcv, j + 4 + half);
            int s3 = __shfl(srcv, j + 6 + half);
            int s4 = __shfl(srcv, j + 8 + half);
            int s5 = __shfl(srcv, j + 10 + half);
            int s6 = __shfl(srcv, j + 12 + half);
            int s7 = __shfl(srcv, j + 14 + half);
            uint32 u0 = hwb[(size_t)s0 * 32 + fl];
            uint32 u1 = hwb[(size_t)s1 * 32 + fl];
            uint32 u2 = hwb[(size_t)s2 * 32 + fl];
            uint32 u3 = hwb[(size_t)s3 * 32 + fl];
            uint32 u4 = hwb[(size_t)s4 * 32 + fl];
            uint32 u5 = hwb[(size_t)s5 * 32 + fl];
            uint32 u6 = hwb[(size_t)s6 * 32 + fl];
            uint32 u7 = hwb[(size_t)s7 * 32 + fl];
            ax0 += bf_lo(u0); ay0 += bf_hi(u0);
            ax1 += bf_lo(u1); ay1 += bf_hi(u1);
            ax0 += bf_lo(u2); ay0 += bf_hi(u2);
            ax1 += bf_lo(u3); ay1 += bf_hi(u3);
            ax0 += bf_lo(u4); ay0 += bf_hi(u4);
            ax1 += bf_lo(u5); ay1 += bf_hi(u5);
            ax0 += bf_lo(u6); ay0 += bf_hi(u6);
            ax1 += bf_lo(u7); ay1 += bf_hi(u7);
        }
    }
    float ax = ax0 + ax1, ay = ay0 + ay1;
    ax += __shfl(ax, fl + 32);
    ay += __shfl(ay, fl + 32);
    if (half == 0) {
        uint32 uself = hwb[(size_t)node * 32 + fl];  // hw'[node] = hw*di
        ax += bf_lo(uself); ay += bf_hi(uself);
        float vx = fmaf(ax * di, scale[2 * fl],     shift[2 * fl]);
        float vy = fmaf(ay * di, scale[2 * fl + 1], shift[2 * fl + 1]);
        vx = fmaxf(vx, 0.f);
        vy = fmaxf(vy, 0.f);
        if (resid) {
            uint32 rv = resid[(size_t)node * 32 + fl];
            vx += bf_lo(rv); vy += bf_hi(rv);
        }
        outb[(size_t)node * 32 + fl] = f2bf(vx) | (f2bf(vy) << 16);
    }
}

// ------- pooling over sorted batch, bf16 input, 8 half-waves x 32 nodes ----
__global__ __launch_bounds__(256) void k_pool(const uint32* __restrict__ hb,
                       const int* __restrict__ batch,
                       float* __restrict__ msum, float* __restrict__ mmax,
                       float* __restrict__ gcnt) {
    int l = threadIdx.x & 31;            // feature pair {2l, 2l+1}
    int hf = threadIdx.x >> 5;           // 8 half-waves per block
    int i0 = blockIdx.x * 256 + hf * 32;
    if (i0 >= NN) return;
    int i1 = i0 + 32; if (i1 > NN) i1 = NN;
    int cur = batch[i0];
    float s0 = 0.f, s1 = 0.f, m0 = 0.f, m1 = 0.f; int c = 0;
    for (int i = i0; i < i1; ++i) {
        int g = batch[i];
        if (g != cur) {
            atomicAdd(&msum[cur * 64 + 2 * l], s0);
            atomicAdd(&msum[cur * 64 + 2 * l + 1], s1);
            atomicMax((unsigned int*)&mmax[cur * 64 + 2 * l], __float_as_uint(m0));
            atomicMax((unsigned int*)&mmax[cur * 64 + 2 * l + 1], __float_as_uint(m1));
            if (l == 0) atomicAdd(&gcnt[cur], (float)c);
            s0 = s1 = m0 = m1 = 0.f; c = 0; cur = g;
        }
        uint32 u = hb[(size_t)i * 32 + l];
        float vx = bf_lo(u), vy = bf_hi(u);
        s0 += vx; s1 += vy; m0 = fmaxf(m0, vx); m1 = fmaxf(m1, vy); ++c;
    }
    atomicAdd(&msum[cur * 64 + 2 * l], s0);
    atomicAdd(&msum[cur * 64 + 2 * l + 1], s1);
    atomicMax((unsigned int*)&mmax[cur * 64 + 2 * l], __float_as_uint(m0));
    atomicMax((unsigned int*)&mmax[cur * 64 + 2 * l + 1], __float_as_uint(m1));
    if (l == 0) atomicAdd(&gcnt[cur], (float)c);
}

// ---------------- MLP head, one block per graph ----------------
__global__ void k_head(const float* __restrict__ msum, const float* __restrict__ mmax,
                       const float* __restrict__ gcnt,
                       const float* __restrict__ Wh1, const float* __restrict__ bh1,
                       const float* __restrict__ Wh2, const float* __restrict__ bh2,
                       const float* __restrict__ Wh3, const float* __restrict__ bh3,
                       float* __restrict__ out) {
    int g = blockIdx.x, t = threadIdx.x;  // 64 threads
    __shared__ float hg[128];
    __shared__ float z1[64];
    __shared__ float z2[32];
    float c = fmaxf(gcnt[g], 1.f);
    hg[t]      = msum[g * 64 + t] / c;
    hg[64 + t] = mmax[g * 64 + t];
    __syncthreads();
    float acc = bh1[t];
#pragma unroll 8
    for (int k = 0; k < 128; ++k) acc = fmaf(hg[k], Wh1[k * 64 + t], acc);
    z1[t] = fmaxf(acc, 0.f);
    __syncthreads();
    if (t < 32) {
        float a2 = bh2[t];
#pragma unroll 8
        for (int k = 0; k < 64; ++k) a2 = fmaf(z1[k], Wh2[k * 32 + t], a2);
        z2[t] = fmaxf(a2, 0.f);
    }
    __syncthreads();
    if (t == 0) {
        float a3 = bh3[0];
        for (int k = 0; k < 32; ++k) a3 = fmaf(z2[k], Wh3[k], a3);
        out[g] = 1.f / (1.f + expf(-a3));
    }
}

// ---------------- launcher ----------------

static inline size_t alignup(size_t x) { return (x + 255) & ~(size_t)255; }

extern "C" void kernel_launch(void* const* d_in, const int* in_sizes, int n_in,
                              void* d_out, int out_size, void* d_ws, size_t ws_size,
                              hipStream_t stream) {
    const float* x   = (const float*)d_in[0];
    const int*   ei  = (const int*)d_in[1];
    const int*   bat = (const int*)d_in[2];
    const float* W1  = (const float*)d_in[3];
    const float* b1  = (const float*)d_in[4];
    const float* g1  = (const float*)d_in[5];
    const float* be1 = (const float*)d_in[6];
    const float* rm1 = (const float*)d_in[7];
    const float* rv1 = (const float*)d_in[8];
    const float* W2  = (const float*)d_in[9];
    const float* b2  = (const float*)d_in[10];
    const float* g2  = (const float*)d_in[11];
    const float* be2 = (const float*)d_in[12];
    const float* rm2 = (const float*)d_in[13];
    const float* rv2 = (const float*)d_in[14];
    const float* Wh1 = (const float*)d_in[15];
    const float* bh1 = (const float*)d_in[16];
    const float* Wh2 = (const float*)d_in[17];
    const float* bh2 = (const float*)d_in[18];
    const float* Wh3 = (const float*)d_in[19];
    const float* bh3 = (const float*)d_in[20];
    float* out = (float*)d_out;

    char* ws = (char*)d_ws;
    size_t o = 0;
    int*   hblk   = (int*)(ws + o);  o = alignup(o + (size_t)P1T * NBUK * 4);
    int*   rbase  = (int*)(ws + o);  o = alignup(o + (size_t)P1T * NBUK * 4);
    int*   bbase  = (int*)(ws + o);  o = alignup(o + (NBUK + 1) * 4);
    int*   offs   = (int*)(ws + o);  o = alignup(o + (NN + 1) * 4);
    uint32* pairs = (uint32*)(ws + o); o = alignup(o + (size_t)EE * 4);
    int*   col    = (int*)(ws + o);  o = alignup(o + (size_t)EE * 4);
    float* dinv   = (float*)(ws + o); o = alignup(o + (size_t)NN * 4);
    float* scb    = (float*)(ws + o); o = alignup(o + 4 * 64 * 4);
    uint32* Wt1b  = (uint32*)(ws + o); o = alignup(o + 64 * (INF_ / 2) * 4);
    uint32* Wt2b  = (uint32*)(ws + o); o = alignup(o + 64 * (HID / 2) * 4);
    float* msum   = (float*)(ws + o); o += (size_t)GG * 64 * 4;
    float* mmax   = (float*)(ws + o); o += (size_t)GG * 64 * 4;
    float* gcnt   = (float*)(ws + o); o += (size_t)GG * 4;
    o = alignup(o);
    uint32* hwb   = (uint32*)(ws + o); o = alignup(o + ((size_t)NN + 1) * 32 * 4);
    uint32* hb    = (uint32*)(ws + o); o = alignup(o + (size_t)NN * 32 * 4);
    (void)ws_size; (void)n_in; (void)in_sizes; (void)out_size;

    // CSR hist + setup + pool-zero (one kernel, 3 block roles)
    k_hist1<<<P1T + SETUP_B + ZERO_B, 256, 0, stream>>>(
        ei, hblk, b1, g1, be1, rm1, rv1, b2, g2, be2, rm2, rv2, scb,
        W1, Wt1b, W2, Wt2b, hwb, msum);
    k_scan2<<<1, 512, 0, stream>>>(hblk, bbase, rbase, offs);
    k_p1b<<<P1T, 256, 0, stream>>>(ei, hblk, rbase, pairs);
    k_p2<<<NBUK, 256, 0, stream>>>(pairs, bbase, offs, dinv, col);

    // layer 1 (GEMM outputs pre-scaled by dinv; activations packed bf16)
    k_gemm_mfma<INF_, 0><<<(NN + 63) / 64, 256, 0, stream>>>(x, Wt1b, dinv, hwb, NN);
    k_gcn_gather<<<(NN + 3) / 4, 256, 0, stream>>>(hwb, col, offs, dinv,
                                                   scb, scb + 64, nullptr, hb);
    // layer 2 (residual, in-place into hb)
    k_gemm_mfma<HID, 1><<<(NN + 63) / 64, 256, 0, stream>>>(hb, Wt2b, dinv, hwb, NN);
    k_gcn_gather<<<(NN + 3) / 4, 256, 0, stream>>>(hwb, col, offs, dinv,
                                                   scb + 128, scb + 192, hb, hb);
    // pooling + head
    k_pool<<<(NN + 255) / 256, 256, 0, stream>>>(hb, bat, msum, mmax, gcnt);
    k_head<<<GG, 64, 0, stream>>>(msum, mmax, gcnt, Wh1, bh1, Wh2, bh2, Wh3, bh3, out);
}

// Round 13
// 309.869 us; speedup vs baseline: 1.1305x; 1.1305x over previous
//
#include <hip/hip_runtime.h>
#include <math.h>

#define NN 100000
#define EE 1600000
#define GG 512
#define INF_ 128
#define HID 64
#define EPS 1e-5f

#define NBUK 391          // ceil(NN/256), bucket = dst >> 8
#define P1T 98            // CSR tiles: 4096 int4 = 16384 edges each
#define SETUP_B 25        // covers setup span (6224 < 25*256)
#define POOL_WORDS (GG * 64 * 2 + GG)
#define ZERO_B ((POOL_WORDS + 255) / 256)

typedef unsigned int uint32;
typedef __attribute__((ext_vector_type(8))) short bf16x8;
typedef __attribute__((ext_vector_type(4))) float f32x4;
typedef __attribute__((ext_vector_type(2))) float f32x2;

// bf16 helpers: RNE pack, shift decode
static __device__ inline uint32 f2bf(float f) {
    uint32 u = __float_as_uint(f);
    return (u + 0x7FFFu + ((u >> 16) & 1u)) >> 16;
}
static __device__ inline float bf_lo(uint32 u) { return __uint_as_float(u << 16); }
static __device__ inline float bf_hi(uint32 u) { return __uint_as_float(u & 0xFFFF0000u); }

// R10: edge weight folded into features (hw' = hw*dinv[row]); tails -> row NN.
// R11: 32-lane/2-segment gather layout; activations packed bf16.
// R12 FAILED: LDS-staged scatter -> 252K LDS bank conflicts, p1b 51us. Reverted.
// R13: gathered features fp8 e4m3 (row = 64B = 1 line, array 6.4MB ~L2-resident);
// hwb's only consumer is the gather, so only the aggregation loses precision.

// blocks [0,P1T): per-block dst histogram. [P1T,+25): setup. rest: zero pool.
__global__ __launch_bounds__(256) void k_hist1(const int* __restrict__ ei,
        int* __restrict__ hblk,
        const float* b1, const float* g1, const float* be1,
        const float* rm1, const float* rv1,
        const float* b2, const float* g2, const float* be2,
        const float* rm2, const float* rv2, float* sc,
        const float* W1, uint32* Wt1b, const float* W2, uint32* Wt2b,
        uint32* hwb, float* poolz) {
    int b = blockIdx.x, t = threadIdx.x;
    if (b < P1T) {
        __shared__ int h[NBUK];
        for (int i = t; i < NBUK; i += 256) h[i] = 0;
        __syncthreads();
        const int4* dst4 = (const int4*)(ei + EE);
        int base4 = b * 4096;
        for (int j = 0; j < 16; ++j) {
            int i4 = base4 + j * 256 + t;
            if (i4 < EE / 4) {
                int4 d = dst4[i4];
                atomicAdd(&h[d.x >> 8], 1);
                atomicAdd(&h[d.y >> 8], 1);
                atomicAdd(&h[d.z >> 8], 1);
                atomicAdd(&h[d.w >> 8], 1);
            }
        }
        __syncthreads();
        for (int i = t; i < NBUK; i += 256) hblk[i * P1T + b] = h[i];
    } else if (b < P1T + SETUP_B) {
        int i = (b - P1T) * 256 + t;
        if (i < 4096) {                       // Wt1b: K=128
            int n = i >> 6, kp = (i & 63) * 2;
            Wt1b[i] = f2bf(W1[(size_t)kp * 64 + n]) |
                      (f2bf(W1[(size_t)(kp + 1) * 64 + n]) << 16);
        } else if (i < 6144) {                // Wt2b: K=64
            int j = i - 4096;
            int n = j >> 5, kp = (j & 31) * 2;
            Wt2b[j] = f2bf(W2[(size_t)kp * 64 + n]) |
                      (f2bf(W2[(size_t)(kp + 1) * 64 + n]) << 16);
        } else if (i < 6208) {                // BN fold
            int l = i - 6144;
            float s1 = g1[l] * rsqrtf(rv1[l] + EPS);
            sc[l]       = s1;
            sc[64 + l]  = (b1[l] - rm1[l]) * s1 + be1[l];
            float s2 = g2[l] * rsqrtf(rv2[l] + EPS);
            sc[128 + l] = s2;
            sc[192 + l] = (b2[l] - rm2[l]) * s2 + be2[l];
        } else if (i < 6224) {                // zero fp8 row NN of hwb (16 uints)
            hwb[(size_t)NN * 16 + (i - 6208)] = 0u;
        }
    } else {
        int i = (b - P1T - SETUP_B) * 256 + t;
        if (i < POOL_WORDS) poolz[i] = 0.f;
    }
}

// one block, 512 threads: bucket totals + scan -> bbase; per-block run bases.
__global__ void k_scan2(const int* __restrict__ hblk, int* __restrict__ bbase,
                        int* __restrict__ rbase, int* __restrict__ offs) {
    __shared__ int wsum[8];
    int t = threadIdx.x;  // 512
    int lane = t & 63, w = t >> 6;
    int c = 0;
    if (t < NBUK)
        for (int b = 0; b < P1T; ++b) c += hblk[t * P1T + b];
    int v = c;
    for (int d = 1; d < 64; d <<= 1) { int n = __shfl_up(v, d); if (lane >= d) v += n; }
    if (lane == 63) wsum[w] = v;
    __syncthreads();
    int pre = 0;
    for (int q = 0; q < w; ++q) pre += wsum[q];
    int excl = pre + v - c;
    if (t <= NBUK) bbase[t] = excl;
    if (t == 0) offs[NN] = EE;
    if (t < NBUK) {
        int run = excl;
        for (int b = 0; b < P1T; ++b) {
            rbase[t * P1T + b] = run;
            run += hblk[t * P1T + b];
        }
    }
}

// scatter packed (src<<8)|(dst&255) into CSR-ordered bucket regions (R11 form)
__global__ __launch_bounds__(256) void k_p1b(const int* __restrict__ ei,
                                             const int* __restrict__ rbase,
                                             uint32* __restrict__ pairs) {
    __shared__ int h[NBUK];
    int b = blockIdx.x, t = threadIdx.x;
    for (int i = t; i < NBUK; i += 256) h[i] = rbase[i * P1T + b];
    __syncthreads();
    const int4* src4 = (const int4*)ei;
    const int4* dst4 = (const int4*)(ei + EE);
    int base4 = b * 4096;
    for (int j = 0; j < 16; ++j) {
        int i4 = base4 + j * 256 + t;
        if (i4 < EE / 4) {
            int4 d = dst4[i4];
            int4 s = src4[i4];
            int p0 = atomicAdd(&h[d.x >> 8], 1);
            pairs[p0] = ((uint32)s.x << 8) | (uint32)(d.x & 255);
            int p1 = atomicAdd(&h[d.y >> 8], 1);
            pairs[p1] = ((uint32)s.y << 8) | (uint32)(d.y & 255);
            int p2 = atomicAdd(&h[d.z >> 8], 1);
            pairs[p2] = ((uint32)s.z << 8) | (uint32)(d.z & 255);
            int p3 = atomicAdd(&h[d.w >> 8], 1);
            pairs[p3] = ((uint32)s.w << 8) | (uint32)(d.w & 255);
        }
    }
}

// per-bucket (256 nodes) CSR finalize in LDS: count, scan, scatter col (R11)
__global__ __launch_bounds__(256) void k_p2(const uint32* __restrict__ pairs,
                                            const int* __restrict__ bbase,
                                            int* __restrict__ offs, float* __restrict__ dinv,
                                            int* __restrict__ col) {
    int b = blockIdx.x, t = threadIdx.x;
    int nbase = b << 8;
    int ebase = bbase[b], eend = bbase[b + 1];
    int m = eend - ebase;
    __shared__ int cnt[256];
    __shared__ int wsum[4];
    cnt[t] = 0;
    __syncthreads();
    for (int i = t; i < m; i += 256)
        atomicAdd(&cnt[pairs[ebase + i] & 255u], 1);
    __syncthreads();
    int c = cnt[t];
    int lane = t & 63, w = t >> 6;
    int v = c;
    for (int d = 1; d < 64; d <<= 1) { int n = __shfl_up(v, d); if (lane >= d) v += n; }
    if (lane == 63) wsum[w] = v;
    __syncthreads();
    int pre = 0;
    for (int q = 0; q < w; ++q) pre += wsum[q];
    int excl = pre + v - c;
    int node = nbase + t;
    if (node < NN) {
        offs[node] = ebase + excl;
        dinv[node] = rsqrtf(1.f + (float)c);
    }
    __syncthreads();
    cnt[t] = excl;
    __syncthreads();
    for (int i = t; i < m; i += 256) {
        uint32 u = pairs[ebase + i];
        int loc = atomicAdd(&cnt[u & 255u], 1);
        col[ebase + loc] = (int)(u >> 8);
    }
}

// ------ MFMA GEMM: X @ [K,64]bf16, rows pre-scaled by dinv -> fp8 packed ---
// XBF16=0: X f32 [nrows][K]. XBF16=1: X bf16-packed uint [nrows][K/2].
// Output: fp8 e4m3 [nrows][16 uints] (64B rows) via HW cvt_pk_fp8_f32.
template <int K, int XBF16>
__global__ __launch_bounds__(256) void k_gemm_mfma(const void* __restrict__ Xv,
                                                   const uint32* __restrict__ Wtb,
                                                   const float* __restrict__ dinv,
                                                   uint32* __restrict__ outb, int nrows) {
    constexpr int KP = K + 8;
    __shared__ alignas(16) unsigned short Al[64 * KP];
    __shared__ alignas(16) unsigned short Bl[64 * KP];
    int tid = threadIdx.x;
    for (int i = tid; i < 64 * (K / 2); i += 256) {
        int n = i / (K / 2), kp = i % (K / 2);
        *(uint32*)&Bl[n * KP + kp * 2] = Wtb[i];
    }
    int r0 = blockIdx.x * 64;
    if (XBF16 == 0) {
        const float* Xb = (const float*)Xv + (size_t)r0 * K;
        int limit = (nrows - r0) * K;
        for (int f = tid * 4; f < 64 * K; f += 1024) {
            float4 v = {0.f, 0.f, 0.f, 0.f};
            if (f + 3 < limit) v = *(const float4*)&Xb[f];
            int row = f / K, kpos = f % K;
            ushort4 pk;
            pk.x = (unsigned short)f2bf(v.x);
            pk.y = (unsigned short)f2bf(v.y);
            pk.z = (unsigned short)f2bf(v.z);
            pk.w = (unsigned short)f2bf(v.w);
            *(ushort4*)&Al[row * KP + kpos] = pk;
        }
    } else {
        const uint32* Xb = (const uint32*)Xv;
        for (int i = tid; i < 64 * (K / 2); i += 256) {
            int row = i / (K / 2), c = i % (K / 2);
            uint32 v = 0;
            if (r0 + row < nrows) v = Xb[(size_t)(r0 + row) * (K / 2) + c];
            *(uint32*)&Al[row * KP + 2 * c] = v;
        }
    }
    __syncthreads();
    int lane = tid & 63, wv = tid >> 6;
    int m = lane & 15, quad = lane >> 4;
    f32x4 acc0 = {0.f, 0.f, 0.f, 0.f}, acc1 = acc0, acc2 = acc0, acc3 = acc0;
    int arow = wv * 16 + m;
#pragma unroll
    for (int k0 = 0; k0 < K; k0 += 32) {
        int koff = k0 + quad * 8;
        bf16x8 a = *(const bf16x8*)&Al[arow * KP + koff];
        bf16x8 b0 = *(const bf16x8*)&Bl[(0 * 16 + m) * KP + koff];
        bf16x8 b1 = *(const bf16x8*)&Bl[(1 * 16 + m) * KP + koff];
        bf16x8 b2 = *(const bf16x8*)&Bl[(2 * 16 + m) * KP + koff];
        bf16x8 b3 = *(const bf16x8*)&Bl[(3 * 16 + m) * KP + koff];
        acc0 = __builtin_amdgcn_mfma_f32_16x16x32_bf16(a, b0, acc0, 0, 0, 0);
        acc1 = __builtin_amdgcn_mfma_f32_16x16x32_bf16(a, b1, acc1, 0, 0, 0);
        acc2 = __builtin_amdgcn_mfma_f32_16x16x32_bf16(a, b2, acc2, 0, 0, 0);
        acc3 = __builtin_amdgcn_mfma_f32_16x16x32_bf16(a, b3, acc3, 0, 0, 0);
    }
    // C/D layout: col = nt*16 + m, row = quad*4 + reg. Pack 4 adjacent cols
    // (lanes m, m+1 via cvt_pk; then m..m+3 via shfl) into one fp8 uint.
    float dsc[4];
#pragma unroll
    for (int reg = 0; reg < 4; ++reg) {
        int row = r0 + wv * 16 + quad * 4 + reg;
        dsc[reg] = (row < nrows) ? dinv[row] : 0.f;
    }
    const float* accs[4] = {(const float*)&acc0, (const float*)&acc1,
                            (const float*)&acc2, (const float*)&acc3};
#pragma unroll
    for (int nt = 0; nt < 4; ++nt) {
#pragma unroll
        for (int reg = 0; reg < 4; ++reg) {
            float val = accs[nt][reg] * dsc[reg];
            float nxt = __shfl_down(val, 1);
            int pair = __builtin_amdgcn_cvt_pk_fp8_f32(val, nxt, 0, false);
            int hi = __shfl_down(pair, 2);
            int row = r0 + wv * 16 + quad * 4 + reg;
            if (((m & 3) == 0) && row < nrows)
                outb[(size_t)row * 16 + nt * 4 + (m >> 2)] =
                    ((uint32)pair & 0xFFFFu) | ((uint32)hi << 16);
        }
    }
}

// ---- fused GCN aggregate + selfloop + BN + ReLU (+resid), fp8 gather ------
// One wave per node; 32 lanes x ushort (2 fp8) cover the 64B row, 2 halves =
// 2 rows per load instruction; 16 edges/iter = 8 shfl + 8 loads + 8 cvt_pk.
// Tail slots read zeroed row NN. Output packed bf16 [NN][32].
__global__ void k_gcn_gather(const unsigned short* __restrict__ hw8,
                             const int* __restrict__ col,
                             const int* __restrict__ offs,
                             const float* __restrict__ dinv, const float* __restrict__ scale,
                             const float* __restrict__ shift, const uint32* __restrict__ resid,
                             uint32* __restrict__ outb) {
    int node = blockIdx.x * 4 + (threadIdx.x >> 6);
    if (node >= NN) return;
    int lane = threadIdx.x & 63;
    int half = lane >> 5;
    int fl = lane & 31;                 // feature pair: {2fl, 2fl+1}
    int e0 = offs[node], e1 = offs[node + 1];
    float di = dinv[node];
    float ax0 = 0.f, ay0 = 0.f, ax1 = 0.f, ay1 = 0.f;
    for (int base = e0; base < e1; base += 64) {
        int m = e1 - base; if (m > 64) m = 64;
        int srcv = NN;                  // zero row for tail slots
        if (lane < m) srcv = col[base + lane];
        for (int j = 0; j < m; j += 16) {
            int s0 = __shfl(srcv, j + half);
            int s1 = __shfl(srcv, j + 2 + half);
            int s2 = __shfl(srcv, j + 4 + half);
            int s3 = __shfl(srcv, j + 6 + half);
            int s4 = __shfl(srcv, j + 8 + half);
            int s5 = __shfl(srcv, j + 10 + half);
            int s6 = __shfl(srcv, j + 12 + half);
            int s7 = __shfl(srcv, j + 14 + half);
            unsigned short u0 = hw8[(size_t)s0 * 32 + fl];
            unsigned short u1 = hw8[(size_t)s1 * 32 + fl];
            unsigned short u2 = hw8[(size_t)s2 * 32 + fl];
            unsigned short u3 = hw8[(size_t)s3 * 32 + fl];
            unsigned short u4 = hw8[(size_t)s4 * 32 + fl];
            unsigned short u5 = hw8[(size_t)s5 * 32 + fl];
            unsigned short u6 = hw8[(size_t)s6 * 32 + fl];
            unsigned short u7 = hw8[(size_t)s7 * 32 + fl];
            f32x2 f0 = __builtin_amdgcn_cvt_pk_f32_fp8((int)u0, false);
            f32x2 f1 = __builtin_amdgcn_cvt_pk_f32_fp8((int)u1, false);
            f32x2 f2 = __builtin_amdgcn_cvt_pk_f32_fp8((int)u2, false);
            f32x2 f3 = __builtin_amdgcn_cvt_pk_f32_fp8((int)u3, false);
            f32x2 f4 = __builtin_amdgcn_cvt_pk_f32_fp8((int)u4, false);
            f32x2 f5 = __builtin_amdgcn_cvt_pk_f32_fp8((int)u5, false);
            f32x2 f6 = __builtin_amdgcn_cvt_pk_f32_fp8((int)u6, false);
            f32x2 f7 = __builtin_amdgcn_cvt_pk_f32_fp8((int)u7, false);
            ax0 += f0.x; ay0 += f0.y;
            ax1 += f1.x; ay1 += f1.y;
            ax0 += f2.x; ay0 += f2.y;
            ax1 += f3.x; ay1 += f3.y;
            ax0 += f4.x; ay0 += f4.y;
            ax1 += f5.x; ay1 += f5.y;
            ax0 += f6.x; ay0 += f6.y;
            ax1 += f7.x; ay1 += f7.y;
        }
    }
    float ax = ax0 + ax1, ay = ay0 + ay1;
    ax += __shfl(ax, fl + 32);
    ay += __shfl(ay, fl + 32);
    if (half == 0) {
        unsigned short us = hw8[(size_t)node * 32 + fl];   // hw'[node] = hw*di
        f32x2 fs = __builtin_amdgcn_cvt_pk_f32_fp8((int)us, false);
        ax += fs.x; ay += fs.y;
        float vx = fmaf(ax * di, scale[2 * fl],     shift[2 * fl]);
        float vy = fmaf(ay * di, scale[2 * fl + 1], shift[2 * fl + 1]);
        vx = fmaxf(vx, 0.f);
        vy = fmaxf(vy, 0.f);
        if (resid) {
            uint32 rv = resid[(size_t)node * 32 + fl];
            vx += bf_lo(rv); vy += bf_hi(rv);
        }
        outb[(size_t)node * 32 + fl] = f2bf(vx) | (f2bf(vy) << 16);
    }
}

// ------- pooling over sorted batch, bf16 input, 8 half-waves x 32 nodes ----
__global__ __launch_bounds__(256) void k_pool(const uint32* __restrict__ hb,
                       const int* __restrict__ batch,
                       float* __restrict__ msum, float* __restrict__ mmax,
                       float* __restrict__ gcnt) {
    int l = threadIdx.x & 31;            // feature pair {2l, 2l+1}
    int hf = threadIdx.x >> 5;           // 8 half-waves per block
    int i0 = blockIdx.x * 256 + hf * 32;
    if (i0 >= NN) return;
    int i1 = i0 + 32; if (i1 > NN) i1 = NN;
    int cur = batch[i0];
    float s0 = 0.f, s1 = 0.f, m0 = 0.f, m1 = 0.f; int c = 0;
    for (int i = i0; i < i1; ++i) {
        int g = batch[i];
        if (g != cur) {
            atomicAdd(&msum[cur * 64 + 2 * l], s0);
            atomicAdd(&msum[cur * 64 + 2 * l + 1], s1);
            atomicMax((unsigned int*)&mmax[cur * 64 + 2 * l], __float_as_uint(m0));
            atomicMax((unsigned int*)&mmax[cur * 64 + 2 * l + 1], __float_as_uint(m1));
            if (l == 0) atomicAdd(&gcnt[cur], (float)c);
            s0 = s1 = m0 = m1 = 0.f; c = 0; cur = g;
        }
        uint32 u = hb[(size_t)i * 32 + l];
        float vx = bf_lo(u), vy = bf_hi(u);
        s0 += vx; s1 += vy; m0 = fmaxf(m0, vx); m1 = fmaxf(m1, vy); ++c;
    }
    atomicAdd(&msum[cur * 64 + 2 * l], s0);
    atomicAdd(&msum[cur * 64 + 2 * l + 1], s1);
    atomicMax((unsigned int*)&mmax[cur * 64 + 2 * l], __float_as_uint(m0));
    atomicMax((unsigned int*)&mmax[cur * 64 + 2 * l + 1], __float_as_uint(m1));
    if (l == 0) atomicAdd(&gcnt[cur], (float)c);
}

// ---------------- MLP head, one block per graph ----------------
__global__ void k_head(const float* __restrict__ msum, const float* __restrict__ mmax,
                       const float* __restrict__ gcnt,
                       const float* __restrict__ Wh1, const float* __restrict__ bh1,
                       const float* __restrict__ Wh2, const float* __restrict__ bh2,
                       const float* __restrict__ Wh3, const float* __restrict__ bh3,
                       float* __restrict__ out) {
    int g = blockIdx.x, t = threadIdx.x;  // 64 threads
    __shared__ float hg[128];
    __shared__ float z1[64];
    __shared__ float z2[32];
    float c = fmaxf(gcnt[g], 1.f);
    hg[t]      = msum[g * 64 + t] / c;
    hg[64 + t] = mmax[g * 64 + t];
    __syncthreads();
    float acc = bh1[t];
#pragma unroll 8
    for (int k = 0; k < 128; ++k) acc = fmaf(hg[k], Wh1[k * 64 + t], acc);
    z1[t] = fmaxf(acc, 0.f);
    __syncthreads();
    if (t < 32) {
        float a2 = bh2[t];
#pragma unroll 8
        for (int k = 0; k < 64; ++k) a2 = fmaf(z1[k], Wh2[k * 32 + t], a2);
        z2[t] = fmaxf(a2, 0.f);
    }
    __syncthreads();
    if (t == 0) {
        float a3 = bh3[0];
        for (int k = 0; k < 32; ++k) a3 = fmaf(z2[k], Wh3[k], a3);
        out[g] = 1.f / (1.f + expf(-a3));
    }
}

// ---------------- launcher ----------------

static inline size_t alignup(size_t x) { return (x + 255) & ~(size_t)255; }

extern "C" void kernel_launch(void* const* d_in, const int* in_sizes, int n_in,
                              void* d_out, int out_size, void* d_ws, size_t ws_size,
                              hipStream_t stream) {
    const float* x   = (const float*)d_in[0];
    const int*   ei  = (const int*)d_in[1];
    const int*   bat = (const int*)d_in[2];
    const float* W1  = (const float*)d_in[3];
    const float* b1  = (const float*)d_in[4];
    const float* g1  = (const float*)d_in[5];
    const float* be1 = (const float*)d_in[6];
    const float* rm1 = (const float*)d_in[7];
    const float* rv1 = (const float*)d_in[8];
    const float* W2  = (const float*)d_in[9];
    const float* b2  = (const float*)d_in[10];
    const float* g2  = (const float*)d_in[11];
    const float* be2 = (const float*)d_in[12];
    const float* rm2 = (const float*)d_in[13];
    const float* rv2 = (const float*)d_in[14];
    const float* Wh1 = (const float*)d_in[15];
    const float* bh1 = (const float*)d_in[16];
    const float* Wh2 = (const float*)d_in[17];
    const float* bh2 = (const float*)d_in[18];
    const float* Wh3 = (const float*)d_in[19];
    const float* bh3 = (const float*)d_in[20];
    float* out = (float*)d_out;

    char* ws = (char*)d_ws;
    size_t o = 0;
    int*   hblk   = (int*)(ws + o);  o = alignup(o + (size_t)P1T * NBUK * 4);
    int*   rbase  = (int*)(ws + o);  o = alignup(o + (size_t)P1T * NBUK * 4);
    int*   bbase  = (int*)(ws + o);  o = alignup(o + (NBUK + 1) * 4);
    int*   offs   = (int*)(ws + o);  o = alignup(o + (NN + 1) * 4);
    uint32* pairs = (uint32*)(ws + o); o = alignup(o + (size_t)EE * 4);
    int*   col    = (int*)(ws + o);  o = alignup(o + (size_t)EE * 4);
    float* dinv   = (float*)(ws + o); o = alignup(o + (size_t)NN * 4);
    float* scb    = (float*)(ws + o); o = alignup(o + 4 * 64 * 4);
    uint32* Wt1b  = (uint32*)(ws + o); o = alignup(o + 64 * (INF_ / 2) * 4);
    uint32* Wt2b  = (uint32*)(ws + o); o = alignup(o + 64 * (HID / 2) * 4);
    float* msum   = (float*)(ws + o); o += (size_t)GG * 64 * 4;
    float* mmax   = (float*)(ws + o); o += (size_t)GG * 64 * 4;
    float* gcnt   = (float*)(ws + o); o += (size_t)GG * 4;
    o = alignup(o);
    uint32* hwb   = (uint32*)(ws + o); o = alignup(o + ((size_t)NN + 1) * 16 * 4);  // fp8
    uint32* hb    = (uint32*)(ws + o); o = alignup(o + (size_t)NN * 32 * 4);        // bf16
    (void)ws_size; (void)n_in; (void)in_sizes; (void)out_size;

    // CSR hist + setup + pool-zero (one kernel, 3 block roles)
    k_hist1<<<P1T + SETUP_B + ZERO_B, 256, 0, stream>>>(
        ei, hblk, b1, g1, be1, rm1, rv1, b2, g2, be2, rm2, rv2, scb,
        W1, Wt1b, W2, Wt2b, hwb, msum);
    k_scan2<<<1, 512, 0, stream>>>(hblk, bbase, rbase, offs);
    k_p1b<<<P1T, 256, 0, stream>>>(ei, rbase, pairs);
    k_p2<<<NBUK, 256, 0, stream>>>(pairs, bbase, offs, dinv, col);

    // layer 1 (GEMM outputs pre-scaled by dinv, packed fp8; activations bf16)
    k_gemm_mfma<INF_, 0><<<(NN + 63) / 64, 256, 0, stream>>>(x, Wt1b, dinv, hwb, NN);
    k_gcn_gather<<<(NN + 3) / 4, 256, 0, stream>>>((const unsigned short*)hwb, col, offs,
                                                   dinv, scb, scb + 64, nullptr, hb);
    // layer 2 (residual, in-place into hb)
    k_gemm_mfma<HID, 1><<<(NN + 63) / 64, 256, 0, stream>>>(hb, Wt2b, dinv, hwb, NN);
    k_gcn_gather<<<(NN + 3) / 4, 256, 0, stream>>>((const unsigned short*)hwb, col, offs,
                                                   dinv, scb + 128, scb + 192, hb, hb);
    // pooling + head
    k_pool<<<(NN + 255) / 256, 256, 0, stream>>>(hb, bat, msum, mmax, gcnt);
    k_head<<<GG, 64, 0, stream>>>(msum, mmax, gcnt, Wh1, bh1, Wh2, bh2, Wh3, bh3, out);
}

// Round 14
// 307.399 us; speedup vs baseline: 1.1396x; 1.0080x over previous
//
#include <hip/hip_runtime.h>
#include <math.h>

#define NN 100000
#define EE 1600000
#define GG 512
#define INF_ 128
#define HID 64
#define EPS 1e-5f

#define NBUK 391          // ceil(NN/256), bucket = dst >> 8
#define P1T 98            // CSR tiles: 4096 int4 = 16384 edges each
#define SETUP_B 25        // covers setup span (6224 < 25*256)
#define POOL_WORDS (GG * 64 * 2 + GG)
#define ZERO_B ((POOL_WORDS + 255) / 256)
#define P2CAP 5120        // LDS stage cap (mean bucket 4092, std ~64; 16 sigma)

typedef unsigned int uint32;
typedef __attribute__((ext_vector_type(8))) short bf16x8;
typedef __attribute__((ext_vector_type(4))) float f32x4;
typedef __attribute__((ext_vector_type(2))) float f32x2;

// bf16 helpers: RNE pack, shift decode
static __device__ inline uint32 f2bf(float f) {
    uint32 u = __float_as_uint(f);
    return (u + 0x7FFFu + ((u >> 16) & 1u)) >> 16;
}
static __device__ inline float bf_lo(uint32 u) { return __uint_as_float(u << 16); }
static __device__ inline float bf_hi(uint32 u) { return __uint_as_float(u & 0xFFFF0000u); }

// R10: edge weight folded into features (hw' = hw*dinv[row]); tails -> row NN.
// R11: 32-lane/2-segment gather layout; activations packed bf16.
// R12 FAILED: LDS-staged *scatter* -> 252K bank conflicts. Lesson: random
//   scatter belongs in L2; only SEQUENTIAL staging belongs in LDS.
// R13: gathered features fp8 e4m3 (64B rows, 6.4MB ~L2-resident).
// R14: p2 stages pairs in LDS once (stride-1, conflict-free), halving its
//   global read traffic; col scatter stays global (R11 proven form).

// blocks [0,P1T): per-block dst histogram. [P1T,+25): setup. rest: zero pool.
__global__ __launch_bounds__(256) void k_hist1(const int* __restrict__ ei,
        int* __restrict__ hblk,
        const float* b1, const float* g1, const float* be1,
        const float* rm1, const float* rv1,
        const float* b2, const float* g2, const float* be2,
        const float* rm2, const float* rv2, float* sc,
        const float* W1, uint32* Wt1b, const float* W2, uint32* Wt2b,
        uint32* hwb, float* poolz) {
    int b = blockIdx.x, t = threadIdx.x;
    if (b < P1T) {
        __shared__ int h[NBUK];
        for (int i = t; i < NBUK; i += 256) h[i] = 0;
        __syncthreads();
        const int4* dst4 = (const int4*)(ei + EE);
        int base4 = b * 4096;
        for (int j = 0; j < 16; ++j) {
            int i4 = base4 + j * 256 + t;
            if (i4 < EE / 4) {
                int4 d = dst4[i4];
                atomicAdd(&h[d.x >> 8], 1);
                atomicAdd(&h[d.y >> 8], 1);
                atomicAdd(&h[d.z >> 8], 1);
                atomicAdd(&h[d.w >> 8], 1);
            }
        }
        __syncthreads();
        for (int i = t; i < NBUK; i += 256) hblk[i * P1T + b] = h[i];
    } else if (b < P1T + SETUP_B) {
        int i = (b - P1T) * 256 + t;
        if (i < 4096) {                       // Wt1b: K=128
            int n = i >> 6, kp = (i & 63) * 2;
            Wt1b[i] = f2bf(W1[(size_t)kp * 64 + n]) |
                      (f2bf(W1[(size_t)(kp + 1) * 64 + n]) << 16);
        } else if (i < 6144) {                // Wt2b: K=64
            int j = i - 4096;
            int n = j >> 5, kp = (j & 31) * 2;
            Wt2b[j] = f2bf(W2[(size_t)kp * 64 + n]) |
                      (f2bf(W2[(size_t)(kp + 1) * 64 + n]) << 16);
        } else if (i < 6208) {                // BN fold
            int l = i - 6144;
            float s1 = g1[l] * rsqrtf(rv1[l] + EPS);
            sc[l]       = s1;
            sc[64 + l]  = (b1[l] - rm1[l]) * s1 + be1[l];
            float s2 = g2[l] * rsqrtf(rv2[l] + EPS);
            sc[128 + l] = s2;
            sc[192 + l] = (b2[l] - rm2[l]) * s2 + be2[l];
        } else if (i < 6224) {                // zero fp8 row NN of hwb (16 uints)
            hwb[(size_t)NN * 16 + (i - 6208)] = 0u;
        }
    } else {
        int i = (b - P1T - SETUP_B) * 256 + t;
        if (i < POOL_WORDS) poolz[i] = 0.f;
    }
}

// one block, 512 threads: bucket totals + scan -> bbase; per-block run bases.
__global__ void k_scan2(const int* __restrict__ hblk, int* __restrict__ bbase,
                        int* __restrict__ rbase, int* __restrict__ offs) {
    __shared__ int wsum[8];
    int t = threadIdx.x;  // 512
    int lane = t & 63, w = t >> 6;
    int c = 0;
    if (t < NBUK)
        for (int b = 0; b < P1T; ++b) c += hblk[t * P1T + b];
    int v = c;
    for (int d = 1; d < 64; d <<= 1) { int n = __shfl_up(v, d); if (lane >= d) v += n; }
    if (lane == 63) wsum[w] = v;
    __syncthreads();
    int pre = 0;
    for (int q = 0; q < w; ++q) pre += wsum[q];
    int excl = pre + v - c;
    if (t <= NBUK) bbase[t] = excl;
    if (t == 0) offs[NN] = EE;
    if (t < NBUK) {
        int run = excl;
        for (int b = 0; b < P1T; ++b) {
            rbase[t * P1T + b] = run;
            run += hblk[t * P1T + b];
        }
    }
}

// scatter packed (src<<8)|(dst&255) into CSR-ordered bucket regions (R11 form)
__global__ __launch_bounds__(256) void k_p1b(const int* __restrict__ ei,
                                             const int* __restrict__ rbase,
                                             uint32* __restrict__ pairs) {
    __shared__ int h[NBUK];
    int b = blockIdx.x, t = threadIdx.x;
    for (int i = t; i < NBUK; i += 256) h[i] = rbase[i * P1T + b];
    __syncthreads();
    const int4* src4 = (const int4*)ei;
    const int4* dst4 = (const int4*)(ei + EE);
    int base4 = b * 4096;
    for (int j = 0; j < 16; ++j) {
        int i4 = base4 + j * 256 + t;
        if (i4 < EE / 4) {
            int4 d = dst4[i4];
            int4 s = src4[i4];
            int p0 = atomicAdd(&h[d.x >> 8], 1);
            pairs[p0] = ((uint32)s.x << 8) | (uint32)(d.x & 255);
            int p1 = atomicAdd(&h[d.y >> 8], 1);
            pairs[p1] = ((uint32)s.y << 8) | (uint32)(d.y & 255);
            int p2 = atomicAdd(&h[d.z >> 8], 1);
            pairs[p2] = ((uint32)s.z << 8) | (uint32)(d.z & 255);
            int p3 = atomicAdd(&h[d.w >> 8], 1);
            pairs[p3] = ((uint32)s.w << 8) | (uint32)(d.w & 255);
        }
    }
}

// per-bucket (256 nodes) CSR finalize; pairs staged ONCE into LDS (stride-1,
// conflict-free); count + scatter both read LDS; col scatter stays global.
__global__ __launch_bounds__(256) void k_p2(const uint32* __restrict__ pairs,
                                            const int* __restrict__ bbase,
                                            int* __restrict__ offs, float* __restrict__ dinv,
                                            int* __restrict__ col) {
    __shared__ uint32 pL[P2CAP];
    __shared__ int cnt[256];
    __shared__ int wsum[4];
    int b = blockIdx.x, t = threadIdx.x;
    int nbase = b << 8;
    int ebase = bbase[b], eend = bbase[b + 1];
    int m = eend - ebase;
    int mm = m < P2CAP ? m : P2CAP;
    for (int i = t; i < mm; i += 256) pL[i] = pairs[ebase + i];
    cnt[t] = 0;
    __syncthreads();
    for (int i = t; i < mm; i += 256) atomicAdd(&cnt[pL[i] & 255u], 1);
    for (int i = P2CAP + t; i < m; i += 256)
        atomicAdd(&cnt[pairs[ebase + i] & 255u], 1);
    __syncthreads();
    int c = cnt[t];
    int lane = t & 63, w = t >> 6;
    int v = c;
    for (int d = 1; d < 64; d <<= 1) { int n = __shfl_up(v, d); if (lane >= d) v += n; }
    if (lane == 63) wsum[w] = v;
    __syncthreads();
    int pre = 0;
    for (int q = 0; q < w; ++q) pre += wsum[q];
    int excl = pre + v - c;
    int node = nbase + t;
    if (node < NN) {
        offs[node] = ebase + excl;
        dinv[node] = rsqrtf(1.f + (float)c);
    }
    __syncthreads();
    cnt[t] = excl;
    __syncthreads();
    for (int i = t; i < mm; i += 256) {
        uint32 u = pL[i];
        int loc = atomicAdd(&cnt[u & 255u], 1);
        col[ebase + loc] = (int)(u >> 8);
    }
    for (int i = P2CAP + t; i < m; i += 256) {
        uint32 u = pairs[ebase + i];
        int loc = atomicAdd(&cnt[u & 255u], 1);
        col[ebase + loc] = (int)(u >> 8);
    }
}

// ------ MFMA GEMM: X @ [K,64]bf16, rows pre-scaled by dinv -> fp8 packed ---
// XBF16=0: X f32 [nrows][K]. XBF16=1: X bf16-packed uint [nrows][K/2].
// Output: fp8 e4m3 [nrows][16 uints] (64B rows) via HW cvt_pk_fp8_f32.
template <int K, int XBF16>
__global__ __launch_bounds__(256) void k_gemm_mfma(const void* __restrict__ Xv,
                                                   const uint32* __restrict__ Wtb,
                                                   const float* __restrict__ dinv,
                                                   uint32* __restrict__ outb, int nrows) {
    constexpr int KP = K + 8;
    __shared__ alignas(16) unsigned short Al[64 * KP];
    __shared__ alignas(16) unsigned short Bl[64 * KP];
    int tid = threadIdx.x;
    for (int i = tid; i < 64 * (K / 2); i += 256) {
        int n = i / (K / 2), kp = i % (K / 2);
        *(uint32*)&Bl[n * KP + kp * 2] = Wtb[i];
    }
    int r0 = blockIdx.x * 64;
    if (XBF16 == 0) {
        const float* Xb = (const float*)Xv + (size_t)r0 * K;
        int limit = (nrows - r0) * K;
        for (int f = tid * 4; f < 64 * K; f += 1024) {
            float4 v = {0.f, 0.f, 0.f, 0.f};
            if (f + 3 < limit) v = *(const float4*)&Xb[f];
            int row = f / K, kpos = f % K;
            ushort4 pk;
            pk.x = (unsigned short)f2bf(v.x);
            pk.y = (unsigned short)f2bf(v.y);
            pk.z = (unsigned short)f2bf(v.z);
            pk.w = (unsigned short)f2bf(v.w);
            *(ushort4*)&Al[row * KP + kpos] = pk;
        }
    } else {
        const uint32* Xb = (const uint32*)Xv;
        for (int i = tid; i < 64 * (K / 2); i += 256) {
            int row = i / (K / 2), c = i % (K / 2);
            uint32 v = 0;
            if (r0 + row < nrows) v = Xb[(size_t)(r0 + row) * (K / 2) + c];
            *(uint32*)&Al[row * KP + 2 * c] = v;
        }
    }
    __syncthreads();
    int lane = tid & 63, wv = tid >> 6;
    int m = lane & 15, quad = lane >> 4;
    f32x4 acc0 = {0.f, 0.f, 0.f, 0.f}, acc1 = acc0, acc2 = acc0, acc3 = acc0;
    int arow = wv * 16 + m;
#pragma unroll
    for (int k0 = 0; k0 < K; k0 += 32) {
        int koff = k0 + quad * 8;
        bf16x8 a = *(const bf16x8*)&Al[arow * KP + koff];
        bf16x8 b0 = *(const bf16x8*)&Bl[(0 * 16 + m) * KP + koff];
        bf16x8 b1 = *(const bf16x8*)&Bl[(1 * 16 + m) * KP + koff];
        bf16x8 b2 = *(const bf16x8*)&Bl[(2 * 16 + m) * KP + koff];
        bf16x8 b3 = *(const bf16x8*)&Bl[(3 * 16 + m) * KP + koff];
        acc0 = __builtin_amdgcn_mfma_f32_16x16x32_bf16(a, b0, acc0, 0, 0, 0);
        acc1 = __builtin_amdgcn_mfma_f32_16x16x32_bf16(a, b1, acc1, 0, 0, 0);
        acc2 = __builtin_amdgcn_mfma_f32_16x16x32_bf16(a, b2, acc2, 0, 0, 0);
        acc3 = __builtin_amdgcn_mfma_f32_16x16x32_bf16(a, b3, acc3, 0, 0, 0);
    }
    // C/D layout: col = nt*16 + m, row = quad*4 + reg. Pack 4 adjacent cols
    // (lanes m, m+1 via cvt_pk; then m..m+3 via shfl) into one fp8 uint.
    float dsc[4];
#pragma unroll
    for (int reg = 0; reg < 4; ++reg) {
        int row = r0 + wv * 16 + quad * 4 + reg;
        dsc[reg] = (row < nrows) ? dinv[row] : 0.f;
    }
    const float* accs[4] = {(const float*)&acc0, (const float*)&acc1,
                            (const float*)&acc2, (const float*)&acc3};
#pragma unroll
    for (int nt = 0; nt < 4; ++nt) {
#pragma unroll
        for (int reg = 0; reg < 4; ++reg) {
            float val = accs[nt][reg] * dsc[reg];
            float nxt = __shfl_down(val, 1);
            int pair = __builtin_amdgcn_cvt_pk_fp8_f32(val, nxt, 0, false);
            int hi = __shfl_down(pair, 2);
            int row = r0 + wv * 16 + quad * 4 + reg;
            if (((m & 3) == 0) && row < nrows)
                outb[(size_t)row * 16 + nt * 4 + (m >> 2)] =
                    ((uint32)pair & 0xFFFFu) | ((uint32)hi << 16);
        }
    }
}

// ---- fused GCN aggregate + selfloop + BN + ReLU (+resid), fp8 gather ------
// One wave per node; 32 lanes x ushort (2 fp8) cover the 64B row, 2 halves =
// 2 rows per load instruction; 16 edges/iter = 8 shfl + 8 loads + 8 cvt_pk.
// Tail slots read zeroed row NN. Output packed bf16 [NN][32].
__global__ void k_gcn_gather(const unsigned short* __restrict__ hw8,
                             const int* __restrict__ col,
                             const int* __restrict__ offs,
                             const float* __restrict__ dinv, const float* __restrict__ scale,
                             const float* __restrict__ shift, const uint32* __restrict__ resid,
                             uint32* __restrict__ outb) {
    int node = blockIdx.x * 4 + (threadIdx.x >> 6);
    if (node >= NN) return;
    int lane = threadIdx.x & 63;
    int half = lane >> 5;
    int fl = lane & 31;                 // feature pair: {2fl, 2fl+1}
    int e0 = offs[node], e1 = offs[node + 1];
    float di = dinv[node];
    float ax0 = 0.f, ay0 = 0.f, ax1 = 0.f, ay1 = 0.f;
    for (int base = e0; base < e1; base += 64) {
        int m = e1 - base; if (m > 64) m = 64;
        int srcv = NN;                  // zero row for tail slots
        if (lane < m) srcv = col[base + lane];
        for (int j = 0; j < m; j += 16) {
            int s0 = __shfl(srcv, j + half);
            int s1 = __shfl(srcv, j + 2 + half);
            int s2 = __shfl(srcv, j + 4 + half);
            int s3 = __shfl(srcv, j + 6 + half);
            int s4 = __shfl(srcv, j + 8 + half);
            int s5 = __shfl(srcv, j + 10 + half);
            int s6 = __shfl(srcv, j + 12 + half);
            int s7 = __shfl(srcv, j + 14 + half);
            unsigned short u0 = hw8[(size_t)s0 * 32 + fl];
            unsigned short u1 = hw8[(size_t)s1 * 32 + fl];
            unsigned short u2 = hw8[(size_t)s2 * 32 + fl];
            unsigned short u3 = hw8[(size_t)s3 * 32 + fl];
            unsigned short u4 = hw8[(size_t)s4 * 32 + fl];
            unsigned short u5 = hw8[(size_t)s5 * 32 + fl];
            unsigned short u6 = hw8[(size_t)s6 * 32 + fl];
            unsigned short u7 = hw8[(size_t)s7 * 32 + fl];
            f32x2 f0 = __builtin_amdgcn_cvt_pk_f32_fp8((int)u0, false);
            f32x2 f1 = __builtin_amdgcn_cvt_pk_f32_fp8((int)u1, false);
            f32x2 f2 = __builtin_amdgcn_cvt_pk_f32_fp8((int)u2, false);
            f32x2 f3 = __builtin_amdgcn_cvt_pk_f32_fp8((int)u3, false);
            f32x2 f4 = __builtin_amdgcn_cvt_pk_f32_fp8((int)u4, false);
            f32x2 f5 = __builtin_amdgcn_cvt_pk_f32_fp8((int)u5, false);
            f32x2 f6 = __builtin_amdgcn_cvt_pk_f32_fp8((int)u6, false);
            f32x2 f7 = __builtin_amdgcn_cvt_pk_f32_fp8((int)u7, false);
            ax0 += f0.x; ay0 += f0.y;
            ax1 += f1.x; ay1 += f1.y;
            ax0 += f2.x; ay0 += f2.y;
            ax1 += f3.x; ay1 += f3.y;
            ax0 += f4.x; ay0 += f4.y;
            ax1 += f5.x; ay1 += f5.y;
            ax0 += f6.x; ay0 += f6.y;
            ax1 += f7.x; ay1 += f7.y;
        }
    }
    float ax = ax0 + ax1, ay = ay0 + ay1;
    ax += __shfl(ax, fl + 32);
    ay += __shfl(ay, fl + 32);
    if (half == 0) {
        unsigned short us = hw8[(size_t)node * 32 + fl];   // hw'[node] = hw*di
        f32x2 fs = __builtin_amdgcn_cvt_pk_f32_fp8((int)us, false);
        ax += fs.x; ay += fs.y;
        float vx = fmaf(ax * di, scale[2 * fl],     shift[2 * fl]);
        float vy = fmaf(ay * di, scale[2 * fl + 1], shift[2 * fl + 1]);
        vx = fmaxf(vx, 0.f);
        vy = fmaxf(vy, 0.f);
        if (resid) {
            uint32 rv = resid[(size_t)node * 32 + fl];
            vx += bf_lo(rv); vy += bf_hi(rv);
        }
        outb[(size_t)node * 32 + fl] = f2bf(vx) | (f2bf(vy) << 16);
    }
}

// ------- pooling over sorted batch, bf16 input, 8 half-waves x 32 nodes ----
__global__ __launch_bounds__(256) void k_pool(const uint32* __restrict__ hb,
                       const int* __restrict__ batch,
                       float* __restrict__ msum, float* __restrict__ mmax,
                       float* __restrict__ gcnt) {
    int l = threadIdx.x & 31;            // feature pair {2l, 2l+1}
    int hf = threadIdx.x >> 5;           // 8 half-waves per block
    int i0 = blockIdx.x * 256 + hf * 32;
    if (i0 >= NN) return;
    int i1 = i0 + 32; if (i1 > NN) i1 = NN;
    int cur = batch[i0];
    float s0 = 0.f, s1 = 0.f, m0 = 0.f, m1 = 0.f; int c = 0;
    for (int i = i0; i < i1; ++i) {
        int g = batch[i];
        if (g != cur) {
            atomicAdd(&msum[cur * 64 + 2 * l], s0);
            atomicAdd(&msum[cur * 64 + 2 * l + 1], s1);
            atomicMax((unsigned int*)&mmax[cur * 64 + 2 * l], __float_as_uint(m0));
            atomicMax((unsigned int*)&mmax[cur * 64 + 2 * l + 1], __float_as_uint(m1));
            if (l == 0) atomicAdd(&gcnt[cur], (float)c);
            s0 = s1 = m0 = m1 = 0.f; c = 0; cur = g;
        }
        uint32 u = hb[(size_t)i * 32 + l];
        float vx = bf_lo(u), vy = bf_hi(u);
        s0 += vx; s1 += vy; m0 = fmaxf(m0, vx); m1 = fmaxf(m1, vy); ++c;
    }
    atomicAdd(&msum[cur * 64 + 2 * l], s0);
    atomicAdd(&msum[cur * 64 + 2 * l + 1], s1);
    atomicMax((unsigned int*)&mmax[cur * 64 + 2 * l], __float_as_uint(m0));
    atomicMax((unsigned int*)&mmax[cur * 64 + 2 * l + 1], __float_as_uint(m1));
    if (l == 0) atomicAdd(&gcnt[cur], (float)c);
}

// ---------------- MLP head, one block per graph ----------------
__global__ void k_head(const float* __restrict__ msum, const float* __restrict__ mmax,
                       const float* __restrict__ gcnt,
                       const float* __restrict__ Wh1, const float* __restrict__ bh1,
                       const float* __restrict__ Wh2, const float* __restrict__ bh2,
                       const float* __restrict__ Wh3, const float* __restrict__ bh3,
                       float* __restrict__ out) {
    int g = blockIdx.x, t = threadIdx.x;  // 64 threads
    __shared__ float hg[128];
    __shared__ float z1[64];
    __shared__ float z2[32];
    float c = fmaxf(gcnt[g], 1.f);
    hg[t]      = msum[g * 64 + t] / c;
    hg[64 + t] = mmax[g * 64 + t];
    __syncthreads();
    float acc = bh1[t];
#pragma unroll 8
    for (int k = 0; k < 128; ++k) acc = fmaf(hg[k], Wh1[k * 64 + t], acc);
    z1[t] = fmaxf(acc, 0.f);
    __syncthreads();
    if (t < 32) {
        float a2 = bh2[t];
#pragma unroll 8
        for (int k = 0; k < 64; ++k) a2 = fmaf(z1[k], Wh2[k * 32 + t], a2);
        z2[t] = fmaxf(a2, 0.f);
    }
    __syncthreads();
    if (t == 0) {
        float a3 = bh3[0];
        for (int k = 0; k < 32; ++k) a3 = fmaf(z2[k], Wh3[k], a3);
        out[g] = 1.f / (1.f + expf(-a3));
    }
}

// ---------------- launcher ----------------

static inline size_t alignup(size_t x) { return (x + 255) & ~(size_t)255; }

extern "C" void kernel_launch(void* const* d_in, const int* in_sizes, int n_in,
                              void* d_out, int out_size, void* d_ws, size_t ws_size,
                              hipStream_t stream) {
    const float* x   = (const float*)d_in[0];
    const int*   ei  = (const int*)d_in[1];
    const int*   bat = (const int*)d_in[2];
    const float* W1  = (const float*)d_in[3];
    const float* b1  = (const float*)d_in[4];
    const float* g1  = (const float*)d_in[5];
    const float* be1 = (const float*)d_in[6];
    const float* rm1 = (const float*)d_in[7];
    const float* rv1 = (const float*)d_in[8];
    const float* W2  = (const float*)d_in[9];
    const float* b2  = (const float*)d_in[10];
    const float* g2  = (const float*)d_in[11];
    const float* be2 = (const float*)d_in[12];
    const float* rm2 = (const float*)d_in[13];
    const float* rv2 = (const float*)d_in[14];
    const float* Wh1 = (const float*)d_in[15];
    const float* bh1 = (const float*)d_in[16];
    const float* Wh2 = (const float*)d_in[17];
    const float* bh2 = (const float*)d_in[18];
    const float* Wh3 = (const float*)d_in[19];
    const float* bh3 = (const float*)d_in[20];
    float* out = (float*)d_out;

    char* ws = (char*)d_ws;
    size_t o = 0;
    int*   hblk   = (int*)(ws + o);  o = alignup(o + (size_t)P1T * NBUK * 4);
    int*   rbase  = (int*)(ws + o);  o = alignup(o + (size_t)P1T * NBUK * 4);
    int*   bbase  = (int*)(ws + o);  o = alignup(o + (NBUK + 1) * 4);
    int*   offs   = (int*)(ws + o);  o = alignup(o + (NN + 1) * 4);
    uint32* pairs = (uint32*)(ws + o); o = alignup(o + (size_t)EE * 4);
    int*   col    = (int*)(ws + o);  o = alignup(o + (size_t)EE * 4);
    float* dinv   = (float*)(ws + o); o = alignup(o + (size_t)NN * 4);
    float* scb    = (float*)(ws + o); o = alignup(o + 4 * 64 * 4);
    uint32* Wt1b  = (uint32*)(ws + o); o = alignup(o + 64 * (INF_ / 2) * 4);
    uint32* Wt2b  = (uint32*)(ws + o); o = alignup(o + 64 * (HID / 2) * 4);
    float* msum   = (float*)(ws + o); o += (size_t)GG * 64 * 4;
    float* mmax   = (float*)(ws + o); o += (size_t)GG * 64 * 4;
    float* gcnt   = (float*)(ws + o); o += (size_t)GG * 4;
    o = alignup(o);
    uint32* hwb   = (uint32*)(ws + o); o = alignup(o + ((size_t)NN + 1) * 16 * 4);  // fp8
    uint32* hb    = (uint32*)(ws + o); o = alignup(o + (size_t)NN * 32 * 4);        // bf16
    (void)ws_size; (void)n_in; (void)in_sizes; (void)out_size;

    // CSR hist + setup + pool-zero (one kernel, 3 block roles)
    k_hist1<<<P1T + SETUP_B + ZERO_B, 256, 0, stream>>>(
        ei, hblk, b1, g1, be1, rm1, rv1, b2, g2, be2, rm2, rv2, scb,
        W1, Wt1b, W2, Wt2b, hwb, msum);
    k_scan2<<<1, 512, 0, stream>>>(hblk, bbase, rbase, offs);
    k_p1b<<<P1T, 256, 0, stream>>>(ei, rbase, pairs);
    k_p2<<<NBUK, 256, 0, stream>>>(pairs, bbase, offs, dinv, col);

    // layer 1 (GEMM outputs pre-scaled by dinv, packed fp8; activations bf16)
    k_gemm_mfma<INF_, 0><<<(NN + 63) / 64, 256, 0, stream>>>(x, Wt1b, dinv, hwb, NN);
    k_gcn_gather<<<(NN + 3) / 4, 256, 0, stream>>>((const unsigned short*)hwb, col, offs,
                                                   dinv, scb, scb + 64, nullptr, hb);
    // layer 2 (residual, in-place into hb)
    k_gemm_mfma<HID, 1><<<(NN + 63) / 64, 256, 0, stream>>>(hb, Wt2b, dinv, hwb, NN);
    k_gcn_gather<<<(NN + 3) / 4, 256, 0, stream>>>((const unsigned short*)hwb, col, offs,
                                                   dinv, scb + 128, scb + 192, hb, hb);
    // pooling + head
    k_pool<<<(NN + 255) / 256, 256, 0, stream>>>(hb, bat, msum, mmax, gcnt);
    k_head<<<GG, 64, 0, stream>>>(msum, mmax, gcnt, Wh1, bh1, Wh2, bh2, Wh3, bh3, out);
}